// Round 1
// baseline (153.859 us; speedup 1.0000x reference)
//
#include <hip/hip_runtime.h>
#include <hip/hip_bf16.h>
#include <cstdint>

// Custom vector types (avoid HIP's own short8/float4 struct names)
typedef __attribute__((ext_vector_type(8))) short v8s;   // 8 x bf16 bits (4 VGPRs)
typedef __attribute__((ext_vector_type(4))) float v4f;   // MFMA accumulator

#define NUM_HEADS 8
#define D 256
#define TOK 25088              // 8*56*56 tokens
#define RBLK_PER_HEAD (TOK/16) // 1568 row blocks of 16 tokens
#define CCH 2048               // channels = NUM_HEADS * D

// float -> bf16 bits, round-to-nearest-even
__device__ __forceinline__ short f2bf(float f) {
  unsigned u = __builtin_bit_cast(unsigned, f);
  u = (u + 0x7FFFu + ((u >> 16) & 1u)) >> 16;
  return (short)u;
}

// ---------------------------------------------------------------------------
// Pack weight (8,256,256) fp32 -> fragment-ordered bf16 in d_ws (1 MiB).
// Unit layout: unit = ((head*8 + s)*16 + j)*64 + lane, each unit = 8 bf16 (16B).
// Unit holds B[k = s*32 + (lane>>4)*8 + e][n = j*16 + (lane&15)], e=0..7,
// i.e. exactly the mfma_f32_16x16x32_bf16 B fragment for (kstep s, ntile j).
// ---------------------------------------------------------------------------
__global__ __launch_bounds__(256) void pack_w(const float* __restrict__ w,
                                              short* __restrict__ p) {
  int idx  = blockIdx.x * 256 + threadIdx.x;  // 0..65535
  int lane = idx & 63;
  int j    = (idx >> 6) & 15;
  int s    = (idx >> 10) & 7;
  int head = idx >> 13;
  int n  = j * 16 + (lane & 15);
  int k0 = s * 32 + (lane >> 4) * 8;
  const float* src = w + head * 65536 + k0 * 256 + n;  // weight[head][k][n]
  v8s v;
#pragma unroll
  for (int e = 0; e < 8; ++e) v[e] = f2bf(src[e * 256]);
  *reinterpret_cast<v8s*>(p + (size_t)idx * 8) = v;
}

// ---------------------------------------------------------------------------
// Main grouped GEMM. One wave per (head, 16-token row block).
// A loaded fp32 direct from global (16 dwordx4/lane, all in flight up front),
// converted to bf16 in-register. B fragments are single coalesced 16B/lane
// loads from the packed buffer (L2-resident, 1 MiB total).
// Accumulate full N=256 (16 ntiles) so x is read exactly once.
// ---------------------------------------------------------------------------
__global__ __launch_bounds__(256) void grouped_mm(const float* __restrict__ x,
                                                  const short* __restrict__ pB,
                                                  float* __restrict__ out) {
  int wid  = blockIdx.x * 4 + (threadIdx.x >> 6);
  int lane = threadIdx.x & 63;
  int head = wid / RBLK_PER_HEAD;
  int rblk = wid - head * RBLK_PER_HEAD;
  int t0   = rblk * 16;
  int arow = lane & 15;   // A-fragment row within tile
  int kg   = lane >> 4;   // k-subgroup (8 consecutive k per group)

  const float* aptr  = x + (size_t)(t0 + arow) * CCH + head * D + kg * 8;
  const short* bbase = pB + (size_t)head * 65536 + lane * 8;

  // Load the whole A panel for this wave: 8 ksteps x 8 fp32 per lane.
  v4f a[8][2];
#pragma unroll
  for (int s = 0; s < 8; ++s) {
    a[s][0] = *reinterpret_cast<const v4f*>(aptr + s * 32);
    a[s][1] = *reinterpret_cast<const v4f*>(aptr + s * 32 + 4);
  }

  v4f acc[16];
#pragma unroll
  for (int j = 0; j < 16; ++j) acc[j] = (v4f){0.f, 0.f, 0.f, 0.f};

#pragma unroll
  for (int s = 0; s < 8; ++s) {
    v8s af;
#pragma unroll
    for (int e = 0; e < 4; ++e) {
      af[e]     = f2bf(a[s][0][e]);
      af[4 + e] = f2bf(a[s][1][e]);
    }
#pragma unroll
    for (int j = 0; j < 16; ++j) {
      v8s bf_ = *reinterpret_cast<const v8s*>(bbase + (s * 16 + j) * 512);
      acc[j] = __builtin_amdgcn_mfma_f32_16x16x32_bf16(af, bf_, acc[j], 0, 0, 0);
    }
  }

  // C/D layout (m89-verified): col = lane&15, row = (lane>>4)*4 + reg.
  float* optr = out + (size_t)(t0 + kg * 4) * CCH + head * D + (lane & 15);
#pragma unroll
  for (int j = 0; j < 16; ++j) {
#pragma unroll
    for (int r = 0; r < 4; ++r) {
      optr[(size_t)r * CCH + j * 16] = acc[j][r];
    }
  }
}

extern "C" void kernel_launch(void* const* d_in, const int* in_sizes, int n_in,
                              void* d_out, int out_size, void* d_ws, size_t ws_size,
                              hipStream_t stream) {
  const float* x = (const float*)d_in[0];   // (8,56,56,2048) fp32
  const float* w = (const float*)d_in[1];   // (8,256,256) fp32
  float* out = (float*)d_out;               // (8,56,56,2048) fp32
  short* packed = (short*)d_ws;             // needs 1 MiB

  pack_w<<<256, 256, 0, stream>>>(w, packed);
  // 12544 waves total = 8 heads * 1568 row blocks; 4 waves per 256-thread block
  grouped_mm<<<(NUM_HEADS * RBLK_PER_HEAD) / 4, 256, 0, stream>>>(x, packed, out);
}